// Round 1
// baseline (171.530 us; speedup 1.0000x reference)
//
#include <hip/hip_runtime.h>
#include <hip/hip_bf16.h>
#include <stdint.h>

// Problem constants
#define BATCH 16
#define IN_CH 64
#define HIN 56
#define WIN_ 56
#define HO 54
#define WO 54
#define P_PER_B (HO*WO)        // 2916
#define P_PAD 2944             // 23 * 128 (M-tile-friendly padding)
#define OUT_CH 256
#define KDIM 576               // 64*3*3

typedef __attribute__((ext_vector_type(8))) short short8;
typedef __attribute__((ext_vector_type(4))) float f32x4;

__device__ __forceinline__ unsigned short f2bf(float f) {
    unsigned int u = __float_as_uint(f);
    unsigned int r = (u + 0x7fffu + ((u >> 16) & 1u)) >> 16;   // RNE
    return (unsigned short)r;
}

// ---------------- prep kernels ----------------

// One block (64 threads = 1 wave) per output channel: bf16-convert weight row,
// compute ||w_o||^2 in fp32.
__global__ void prep_weight(const float* __restrict__ w, short* __restrict__ wbf,
                            float* __restrict__ c2) {
    int o = blockIdx.x;
    int lane = threadIdx.x;           // 0..63
    float s = 0.f;
    #pragma unroll
    for (int j = 0; j < 9; ++j) {     // 576 = 9*64
        int k = j * 64 + lane;
        float v = w[o * KDIM + k];
        s += v * v;
        ((unsigned short*)wbf)[o * KDIM + k] = f2bf(v);
    }
    #pragma unroll
    for (int off = 32; off > 0; off >>= 1) s += __shfl_down(s, off);
    if (lane == 0) c2[o] = s;
}

// s[b, h, w] = sum_c x[b,c,h,w]^2   (16*3136 = 50176 threads)
__global__ void sqsum_kernel(const float* __restrict__ x, float* __restrict__ s) {
    int t = blockIdx.x * 256 + threadIdx.x;     // exactly 196*256 = 50176
    int b = t / (HIN * WIN_);
    int r = t % (HIN * WIN_);
    const float* xp = x + (size_t)b * IN_CH * HIN * WIN_ + r;
    float acc = 0.f;
    #pragma unroll 8
    for (int c = 0; c < IN_CH; ++c) {
        float v = xp[c * HIN * WIN_];
        acc += v * v;
    }
    s[t] = acc;
}

// w2[b*P_PAD + p] = 3x3 window sum of s  (= ||win_p||^2, fp32 from original data)
__global__ void w2_kernel(const float* __restrict__ s, float* __restrict__ w2) {
    int t = blockIdx.x * 256 + threadIdx.x;
    if (t >= BATCH * P_PER_B) return;
    int b = t / P_PER_B, p = t % P_PER_B;
    int oh = p / WO, ow = p % WO;
    const float* sp = s + b * HIN * WIN_ + oh * WIN_ + ow;
    float acc = 0.f;
    #pragma unroll
    for (int kh = 0; kh < 3; ++kh)
        #pragma unroll
        for (int kw = 0; kw < 3; ++kw)
            acc += sp[kh * WIN_ + kw];
    w2[b * P_PAD + p] = acc;
}

// im2col to bf16: patches[(b*P_PAD + p)*576 + k], k = c*9 + kh*3 + kw (unfold order)
__global__ void im2col_kernel(const float* __restrict__ x, short* __restrict__ patches) {
    int tid = blockIdx.x * 256 + threadIdx.x;   // exactly 104976*256 = 16*2916*576
    int k = tid % KDIM;
    int r = tid / KDIM;
    int p = r % P_PER_B, b = r / P_PER_B;
    int c = k / 9, rem = k % 9;
    int kh = rem / 3, kw = rem % 3;
    int oh = p / WO, ow = p % WO;
    float v = x[(((b * IN_CH + c) * HIN) + oh + kh) * WIN_ + ow + kw];
    ((unsigned short*)patches)[(size_t)(b * P_PAD + p) * KDIM + k] = f2bf(v);
}

// ---------------- GEMM + RBF epilogue ----------------
// C[m][n] = sum_k patches[m][k] * wbf[n][k];  out = exp(-(w2[m]+c2[n]-2C)/8)
// 128x128 block tile, BK=64, 4 waves each 64x64, mfma_f32_16x16x32_bf16.

#define AS1(p) ((const __attribute__((address_space(1))) void*)(p))
#define AS3(p) ((__attribute__((address_space(3))) void*)(p))

__global__ __launch_bounds__(256) void gemm_rbf(
    const short* __restrict__ patches, const short* __restrict__ wbf,
    const float* __restrict__ w2, const float* __restrict__ c2,
    float* __restrict__ out) {
    __shared__ __align__(16) short lds_a[128 * 64];   // [m][k], row = 128 B
    __shared__ __align__(16) short lds_b[128 * 64];   // [n][k]

    const int mt = blockIdx.x;                 // 0..367
    const int b  = mt / 23;
    const int p0 = (mt % 23) * 128;
    const int n0 = blockIdx.y * 128;

    const int tid  = threadIdx.x;
    const int wave = tid >> 6;
    const int lane = tid & 63;
    const int r16  = lane & 15;
    const int quad = lane >> 4;
    const int wm = (wave >> 1) * 64;           // wave's m-offset in tile
    const int wn = (wave & 1) * 64;            // wave's n-offset in tile

    // staging lane mapping: 8 lanes per row, 16 B per lane
    const int srow = lane >> 3;                // 0..7
    const int scol = lane & 7;                 // 16B chunk index
    const size_t arow0 = (size_t)(b * P_PAD + p0);

    f32x4 acc[4][4];
    #pragma unroll
    for (int i = 0; i < 4; ++i)
        #pragma unroll
        for (int j = 0; j < 4; ++j)
            acc[i][j] = (f32x4){0.f, 0.f, 0.f, 0.f};

    for (int kt = 0; kt < KDIM / 64; ++kt) {   // 9 iters
        const int k0 = kt * 64;
        #pragma unroll
        for (int i = 0; i < 4; ++i) {
            int rb  = wave * 4 + i;            // 0..15, wave-uniform
            int row = rb * 8 + srow;
            const short* ga = patches + (arow0 + row) * KDIM + k0 + scol * 8;
            __builtin_amdgcn_global_load_lds(AS1(ga), AS3(lds_a + rb * 512), 16, 0, 0);
            const short* gb = wbf + (size_t)(n0 + row) * KDIM + k0 + scol * 8;
            __builtin_amdgcn_global_load_lds(AS1(gb), AS3(lds_b + rb * 512), 16, 0, 0);
        }
        __syncthreads();                       // drains vmcnt + barrier
        #pragma unroll
        for (int ks = 0; ks < 2; ++ks) {       // two k-steps of 32
            short8 af[4], bfr[4];
            #pragma unroll
            for (int ms = 0; ms < 4; ++ms)
                af[ms] = *(const short8*)(lds_a + (wm + ms * 16 + r16) * 64 + ks * 32 + quad * 8);
            #pragma unroll
            for (int ns = 0; ns < 4; ++ns)
                bfr[ns] = *(const short8*)(lds_b + (wn + ns * 16 + r16) * 64 + ks * 32 + quad * 8);
            #pragma unroll
            for (int ms = 0; ms < 4; ++ms)
                #pragma unroll
                for (int ns = 0; ns < 4; ++ns)
                    acc[ms][ns] = __builtin_amdgcn_mfma_f32_16x16x32_bf16(
                        af[ms], bfr[ns], acc[ms][ns], 0, 0, 0);
        }
        __syncthreads();                       // protect LDS before next stage
    }

    // Epilogue: D[m][n] lane layout: n = lane&15, m = quad*4 + reg  -> the 4 regs
    // are 4 consecutive positions p for one channel o => float4 store per (ms,ns).
    #pragma unroll
    for (int ms = 0; ms < 4; ++ms) {
        int pl = wm + ms * 16 + quad * 4;
        int p  = p0 + pl;
        if (p >= P_PER_B) continue;            // whole quad out of range (partial tile)
        f32x4 w2v = *(const f32x4*)(w2 + b * P_PAD + p);   // pad region is valid mem
        bool full = (p + 3 < P_PER_B);
        #pragma unroll
        for (int ns = 0; ns < 4; ++ns) {
            int o = n0 + wn + ns * 16 + r16;
            float c2o = c2[o];
            f32x4 v;
            #pragma unroll
            for (int r = 0; r < 4; ++r) {
                float d2 = w2v[r] + c2o - 2.0f * acc[ms][ns][r];
                d2 = fmaxf(d2, 1e-12f);
                v[r] = __expf(-0.125f * d2);
            }
            float* outp = out + ((size_t)(b * OUT_CH + o)) * P_PER_B + p;
            if (full) {
                *(f32x4*)outp = v;
            } else {
                #pragma unroll
                for (int r = 0; r < 4; ++r)
                    if (p + r < P_PER_B) outp[r] = v[r];
            }
        }
    }
}

// ---------------- launch ----------------

extern "C" void kernel_launch(void* const* d_in, const int* in_sizes, int n_in,
                              void* d_out, int out_size, void* d_ws, size_t ws_size,
                              hipStream_t stream) {
    const float* x = (const float*)d_in[0];    // [16,64,56,56]
    const float* w = (const float*)d_in[1];    // [256,576]
    float* out = (float*)d_out;                // [16,256,54,54]

    char* ws = (char*)d_ws;
    // workspace layout (all 16B aligned)
    const size_t patches_bytes = (size_t)BATCH * P_PAD * KDIM * 2;   // 54,263,808
    const size_t wbf_bytes     = (size_t)OUT_CH * KDIM * 2;          // 294,912
    const size_t w2_bytes      = (size_t)BATCH * P_PAD * 4;          // 188,416
    const size_t c2_bytes      = (size_t)OUT_CH * 4;                 // 1,024
    short* patches = (short*)ws;
    short* wbf     = (short*)(ws + patches_bytes);
    float* w2      = (float*)(ws + patches_bytes + wbf_bytes);
    float* c2      = (float*)(ws + patches_bytes + wbf_bytes + w2_bytes);
    float* sq      = (float*)(ws + patches_bytes + wbf_bytes + w2_bytes + c2_bytes);

    hipLaunchKernelGGL(prep_weight, dim3(OUT_CH), dim3(64), 0, stream, w, wbf, c2);
    hipLaunchKernelGGL(sqsum_kernel, dim3(196), dim3(256), 0, stream, x, sq);
    hipLaunchKernelGGL(w2_kernel, dim3((BATCH * P_PER_B + 255) / 256), dim3(256), 0, stream, sq, w2);
    hipLaunchKernelGGL(im2col_kernel, dim3(104976), dim3(256), 0, stream, x, patches);
    hipLaunchKernelGGL(gemm_rbf, dim3(23 * BATCH, OUT_CH / 128), dim3(256), 0, stream,
                       patches, wbf, w2, c2, out);
}

// Round 2
// 105.117 us; speedup vs baseline: 1.6318x; 1.6318x over previous
//
#include <hip/hip_runtime.h>
#include <hip/hip_bf16.h>
#include <stdint.h>

// Problem constants
#define BATCH 16
#define IN_CH 64
#define HIN 56
#define WIN_ 56
#define HO 54
#define WO 54
#define P_PER_B (HO*WO)        // 2916
#define P_PAD 2944             // 23 * 128
#define OUT_CH 256
#define KDIM 576               // 64*3*3
#define NPIX (HIN*WIN_)        // 3136

typedef __attribute__((ext_vector_type(8))) short short8;
typedef __attribute__((ext_vector_type(4))) float f32x4;

__device__ __forceinline__ unsigned short f2bf(float f) {
    unsigned int u = __float_as_uint(f);
    unsigned int r = (u + 0x7fffu + ((u >> 16) & 1u)) >> 16;   // RNE
    return (unsigned short)r;
}

// ---------------- prep kernels ----------------

// One wave per output channel: bf16-convert weight row REORDERED to k' = tap*64 + c
// (tap = kh*3+kw); compute ||w_o||^2 in fp32. K-permutation is legal for the dot
// product as long as A uses the same ordering (it does: tap-major K-loop).
__global__ void prep_weight(const float* __restrict__ w, short* __restrict__ wbf,
                            float* __restrict__ c2) {
    int o = blockIdx.x;
    int lane = threadIdx.x;           // 0..63
    float s = 0.f;
    #pragma unroll
    for (int j = 0; j < 9; ++j) {     // 576 = 9*64
        int k = j * 64 + lane;        // original k = c*9 + tap
        int c = k / 9, tap = k % 9;
        float v = w[o * KDIM + k];
        s += v * v;
        ((unsigned short*)wbf)[o * KDIM + tap * 64 + c] = f2bf(v);
    }
    #pragma unroll
    for (int off = 32; off > 0; off >>= 1) s += __shfl_down(s, off);
    if (lane == 0) c2[o] = s;
}

// NCHW fp32 -> NHWC bf16 transpose (64 pix x 64 ch per block) + fused per-pixel
// channel square-sum s[b, pix].
__global__ __launch_bounds__(256) void transpose_kernel(
    const float* __restrict__ x, short* __restrict__ xT, float* __restrict__ s) {
    __shared__ short lds[64 * 65];
    __shared__ float red[256];
    const int b    = blockIdx.x / 49;
    const int pix0 = (blockIdx.x % 49) * 64;
    const int tid  = threadIdx.x;
    const int quarter = tid >> 6;
    const int pix  = tid & 63;
    const float* xb = x + (size_t)b * IN_CH * NPIX + pix0 + pix;
    float acc = 0.f;
    #pragma unroll
    for (int it = 0; it < 16; ++it) {
        int c = quarter * 16 + it;
        float v = xb[c * NPIX];               // wave reads 256B contiguous
        acc += v * v;
        lds[pix * 65 + c] = (short)f2bf(v);
    }
    red[tid] = acc;
    __syncthreads();
    const int cs = tid & 63;
    short* xTb = xT + ((size_t)b * NPIX + pix0) * 64;
    #pragma unroll
    for (int it = 0; it < 16; ++it) {
        int pixs = quarter * 16 + it;
        xTb[(size_t)pixs * 64 + cs] = lds[pixs * 65 + cs];  // wave writes 128B contiguous
    }
    if (tid < 64)
        s[b * NPIX + pix0 + tid] = red[tid] + red[64 + tid] + red[128 + tid] + red[192 + tid];
}

// w2[b*P_PAD + p] = 3x3 window sum of s  (= ||win_p||^2, fp32)
__global__ void w2_kernel(const float* __restrict__ s, float* __restrict__ w2) {
    int t = blockIdx.x * 256 + threadIdx.x;
    if (t >= BATCH * P_PER_B) return;
    int b = t / P_PER_B, p = t % P_PER_B;
    int oh = p / WO, ow = p % WO;
    const float* sp = s + b * NPIX + oh * WIN_ + ow;
    float acc = 0.f;
    #pragma unroll
    for (int kh = 0; kh < 3; ++kh)
        #pragma unroll
        for (int kw = 0; kw < 3; ++kw)
            acc += sp[kh * WIN_ + kw];
    w2[b * P_PAD + p] = acc;
}

// ---------------- fused im2col GEMM + RBF epilogue ----------------
// C[m][n] = sum_k A[m][k'] * wbf[n][k'] with k' = tap*64 + c; A row m=(b,p) for
// tap (kh,kw) is xT[b, oh+kh, ow+kw, 0..63] -> one contiguous 128B segment.
// 128x128 tile, BK=64 (= one tap), 4 waves each 64x64, mfma_f32_16x16x32_bf16.
// LDS XOR-swizzle: physical 16B-chunk = logical_chunk ^ (row & 7) -> fragment
// ds_read_b128 spreads over all 32 banks (2-way only).

#define AS1(p) ((const __attribute__((address_space(1))) void*)(p))
#define AS3(p) ((__attribute__((address_space(3))) void*)(p))

__constant__ int dtab[9] = {0, 1, 2, 56, 57, 58, 112, 113, 114};  // kh*56+kw

__global__ __launch_bounds__(256) void gemm_rbf(
    const short* __restrict__ xT, const short* __restrict__ wbf,
    const float* __restrict__ w2, const float* __restrict__ c2,
    float* __restrict__ out) {
    __shared__ __align__(16) short lds_a[128 * 64];   // [m][k] swizzled, row = 128 B
    __shared__ __align__(16) short lds_b[128 * 64];   // [n][k] swizzled

    const int mt = blockIdx.x;                 // 0..367
    const int b  = mt / 23;
    const int p0 = (mt % 23) * 128;
    const int n0 = blockIdx.y * 128;

    const int tid  = threadIdx.x;
    const int wave = tid >> 6;
    const int lane = tid & 63;
    const int r16  = lane & 15;
    const int quad = lane >> 4;
    const int wm = (wave >> 1) * 64;
    const int wn = (wave & 1) * 64;

    // staging lane mapping: 8 lanes per row, 16 B per lane, XOR-swizzled source chunk
    const int srow = lane >> 3;                // 0..7
    const int scx  = (lane & 7) ^ srow;        // logical chunk this lane fetches

    const short* xTb = xT + (size_t)b * NPIX * 64;

    // per-lane staging base addresses (4 rows per wave)
    const short* gaB[4];
    const short* gbB[4];
    #pragma unroll
    for (int i = 0; i < 4; ++i) {
        int row = (wave * 4 + i) * 8 + srow;
        int p = p0 + row;
        if (p > P_PER_B - 1) p = P_PER_B - 1;  // clamp pad rows (discarded in epilogue)
        int oh = p / WO, ow = p - oh * WO;
        gaB[i] = xTb + (size_t)(oh * WIN_ + ow) * 64 + scx * 8;
        gbB[i] = wbf + (size_t)(n0 + row) * KDIM + scx * 8;
    }
    const int xq = r16 & 7;                    // fragment-read swizzle key

    f32x4 acc[4][4];
    #pragma unroll
    for (int i = 0; i < 4; ++i)
        #pragma unroll
        for (int j = 0; j < 4; ++j)
            acc[i][j] = (f32x4){0.f, 0.f, 0.f, 0.f};

    #pragma unroll
    for (int kt = 0; kt < 9; ++kt) {           // one tap per iteration
        const int doff = dtab[kt];
        #pragma unroll
        for (int i = 0; i < 4; ++i) {
            int rb = wave * 4 + i;
            __builtin_amdgcn_global_load_lds(AS1(gaB[i] + doff * 64),
                                             AS3(lds_a + rb * 512), 16, 0, 0);
            __builtin_amdgcn_global_load_lds(AS1(gbB[i] + kt * 64),
                                             AS3(lds_b + rb * 512), 16, 0, 0);
        }
        __syncthreads();
        #pragma unroll
        for (int ks = 0; ks < 2; ++ks) {
            short8 af[4], bfr[4];
            #pragma unroll
            for (int ms = 0; ms < 4; ++ms)
                af[ms] = *(const short8*)(lds_a + (wm + ms * 16 + r16) * 64
                                                + (((ks * 4 + quad) ^ xq) * 8));
            #pragma unroll
            for (int ns = 0; ns < 4; ++ns)
                bfr[ns] = *(const short8*)(lds_b + (wn + ns * 16 + r16) * 64
                                                 + (((ks * 4 + quad) ^ xq) * 8));
            #pragma unroll
            for (int ms = 0; ms < 4; ++ms)
                #pragma unroll
                for (int ns = 0; ns < 4; ++ns)
                    acc[ms][ns] = __builtin_amdgcn_mfma_f32_16x16x32_bf16(
                        af[ms], bfr[ns], acc[ms][ns], 0, 0, 0);
        }
        __syncthreads();
    }

    // Epilogue: D layout n = lane&15, m = quad*4 + reg -> 4 regs are 4 consecutive
    // positions p for one channel o => float4 store.
    #pragma unroll
    for (int ms = 0; ms < 4; ++ms) {
        int pl = wm + ms * 16 + quad * 4;
        int p  = p0 + pl;
        if (p >= P_PER_B) continue;
        f32x4 w2v = *(const f32x4*)(w2 + b * P_PAD + p);   // pad region valid mem
        bool full = (p + 3 < P_PER_B);
        #pragma unroll
        for (int ns = 0; ns < 4; ++ns) {
            int o = n0 + wn + ns * 16 + r16;
            float c2o = c2[o];
            f32x4 v;
            #pragma unroll
            for (int r = 0; r < 4; ++r) {
                float d2 = w2v[r] + c2o - 2.0f * acc[ms][ns][r];
                d2 = fmaxf(d2, 1e-12f);
                v[r] = __expf(-0.125f * d2);
            }
            float* outp = out + ((size_t)(b * OUT_CH + o)) * P_PER_B + p;
            if (full) {
                *(f32x4*)outp = v;
            } else {
                #pragma unroll
                for (int r = 0; r < 4; ++r)
                    if (p + r < P_PER_B) outp[r] = v[r];
            }
        }
    }
}

// ---------------- launch ----------------

extern "C" void kernel_launch(void* const* d_in, const int* in_sizes, int n_in,
                              void* d_out, int out_size, void* d_ws, size_t ws_size,
                              hipStream_t stream) {
    const float* x = (const float*)d_in[0];    // [16,64,56,56]
    const float* w = (const float*)d_in[1];    // [256,576]
    float* out = (float*)d_out;                // [16,256,54,54]

    char* ws = (char*)d_ws;
    const size_t wbf_bytes = (size_t)OUT_CH * KDIM * 2;            // 294,912
    const size_t c2_bytes  = 1024;                                 // OUT_CH*4
    const size_t w2_bytes  = (size_t)BATCH * P_PAD * 4;            // 188,416
    const size_t s_bytes   = (size_t)BATCH * NPIX * 4;             // 200,704
    short* wbf = (short*)ws;
    float* c2  = (float*)(ws + wbf_bytes);
    float* w2  = (float*)(ws + wbf_bytes + c2_bytes);
    float* s   = (float*)(ws + wbf_bytes + c2_bytes + w2_bytes);
    short* xT  = (short*)(ws + wbf_bytes + c2_bytes + w2_bytes + s_bytes);  // 6.4 MB

    hipLaunchKernelGGL(prep_weight, dim3(OUT_CH), dim3(64), 0, stream, w, wbf, c2);
    hipLaunchKernelGGL(transpose_kernel, dim3(16 * 49), dim3(256), 0, stream, x, xT, s);
    hipLaunchKernelGGL(w2_kernel, dim3((BATCH * P_PER_B + 255) / 256), dim3(256), 0, stream, s, w2);
    hipLaunchKernelGGL(gemm_rbf, dim3(23 * BATCH, OUT_CH / 128), dim3(256), 0, stream,
                       xT, wbf, w2, c2, out);
}